// Round 22
// baseline (1068.187 us; speedup 1.0000x reference)
//
#include <hip/hip_runtime.h>
#include <hip/hip_bf16.h>
#include <stdint.h>

typedef __attribute__((ext_vector_type(8))) short short8;
typedef __attribute__((ext_vector_type(4))) float f32x4;
typedef __attribute__((ext_vector_type(16))) float f32x16;

#define DEVINL static __device__ __forceinline__

// ---------- helpers ----------
DEVINL unsigned short f2bf(float x) {
  union { float f; unsigned int u; } c; c.f = x;
  unsigned int u = c.u;
  u += 0x7fffu + ((u >> 16) & 1u);   // RNE
  return (unsigned short)(u >> 16);
}

DEVINL f32x4 mfma16(short8 a, short8 b, f32x4 c) {
  return __builtin_amdgcn_mfma_f32_16x16x32_bf16(a, b, c, 0, 0, 0);
}

DEVINL f32x16 mfma32(short8 a, short8 b, f32x16 c) {
  return __builtin_amdgcn_mfma_f32_32x32x16_bf16(a, b, c, 0, 0, 0);
}

DEVINL unsigned int cvtpk(float lo, float hi_) {
  unsigned int r;
  asm("v_cvt_pk_bf16_f32 %0, %1, %2" : "=v"(r) : "v"(lo), "v"(hi_));
  return r;
}

DEVINL void pl32swap(unsigned int& a, unsigned int& b) {
  asm("v_permlane32_swap_b32 %0, %1" : "+v"(a), "+v"(b));
}

DEVINL void gload16(const void* g, void* l) {
  __builtin_amdgcn_global_load_lds((const __attribute__((address_space(1))) void*)g,
                                   (__attribute__((address_space(3))) void*)l, 16, 0, 0);
}

// ---------- problem constants ----------
static constexpr int BB = 2, SS = 2048, HH = 3072;
static constexpr int NH = 24, NKV = 8, HD = 128, NREP = 3;
static constexpr int MM = BB * SS;            // 4096 token rows
static constexpr int KQ = NH * HD;            // 3072
static constexpr int KKV = NKV * HD;          // 1024
static constexpr int KV2 = 2 * KKV;           // 2048 (fused K|V row stride)

// ---------- fused prep: hidden fp32->bf16 + mask nonzero flag (grid-strided) ----------
__global__ void k_prep(const float* __restrict__ hidden, unsigned short* __restrict__ outX,
                       int n4x, const float* __restrict__ mask, int n4m,
                       int* __restrict__ flag) {
  const int stride = gridDim.x * 256;
  const int t0 = blockIdx.x * 256 + threadIdx.x;
  for (int i = t0; i < n4x; i += stride) {
    float4 v = reinterpret_cast<const float4*>(hidden)[i];
    ushort4 o;
    o.x = f2bf(v.x); o.y = f2bf(v.y); o.z = f2bf(v.z); o.w = f2bf(v.w);
    reinterpret_cast<ushort4*>(outX)[i] = o;
  }
  bool any = false;
  for (int i = t0; i < n4m; i += stride) {
    float4 v = reinterpret_cast<const float4*>(mask)[i];
    any |= (v.x != 0.f) || (v.y != 0.f) || (v.z != 0.f) || (v.w != 0.f);
  }
  if (__any(any) && (threadIdx.x & 63) == 0) atomicOr(flag, 1);
}

// ---------- all-weights transpose+convert: z selects {Wq,Wo,Wk,Wv} ----------
__global__ void k_tcvt4(const float* __restrict__ Wq, const float* __restrict__ Wo,
                        const float* __restrict__ Wk, const float* __restrict__ Wv,
                        unsigned short* __restrict__ WqT, unsigned short* __restrict__ WoT,
                        unsigned short* __restrict__ WkT, unsigned short* __restrict__ WvT,
                        float qscale) {
  __shared__ float t[32][33];
  const int z = blockIdx.z;
  const int C = (z < 2) ? KQ : KKV;
  const int c0 = blockIdx.x * 32;
  if (c0 >= C) return;
  const float* in = (z == 0) ? Wq : (z == 1) ? Wo : (z == 2) ? Wk : Wv;
  unsigned short* out = (z == 0) ? WqT : (z == 1) ? WoT : (z == 2) ? WkT : WvT;
  const float sc = (z == 0) ? qscale : 1.0f;
  int tx = threadIdx.x & 31, ty = threadIdx.x >> 5;
  int r0 = blockIdx.y * 32;
#pragma unroll
  for (int i = 0; i < 32; i += 8)
    t[ty + i][tx] = in[(long)(r0 + ty + i) * C + c0 + tx];
  __syncthreads();
#pragma unroll
  for (int i = 0; i < 32; i += 8)
    out[(long)(c0 + ty + i) * HH + r0 + tx] = f2bf(t[tx][ty + i] * sc);
}

// ---------- V transpose (bf16), 64x64 tiles, ushort4 I/O ----------
__global__ void k_vt(const unsigned short* __restrict__ KV, unsigned short* __restrict__ VT) {
  __shared__ unsigned short t[64][66];
  int b = blockIdx.z >> 3, kv = blockIdx.z & 7;
  int tx = threadIdx.x & 15, ty = threadIdx.x >> 4;   // 16 x 16
  int d0 = blockIdx.x * 64, s0 = blockIdx.y * 64;
  const unsigned short* src = KV + ((long)b * SS) * KV2 + KKV + kv * HD;
  unsigned short* dst = VT + (long)(b * NKV + kv) * HD * SS;
#pragma unroll
  for (int i = 0; i < 64; i += 16) {
    ushort4 v = *reinterpret_cast<const ushort4*>(src + (long)(s0 + ty + i) * KV2 + d0 + tx * 4);
    t[ty + i][tx * 4 + 0] = v.x; t[ty + i][tx * 4 + 1] = v.y;
    t[ty + i][tx * 4 + 2] = v.z; t[ty + i][tx * 4 + 3] = v.w;
  }
  __syncthreads();
#pragma unroll
  for (int i = 0; i < 64; i += 16) {
    ushort4 w;
    w.x = t[tx * 4 + 0][ty + i]; w.y = t[tx * 4 + 1][ty + i];
    w.z = t[tx * 4 + 2][ty + i]; w.w = t[tx * 4 + 3][ty + i];
    *reinterpret_cast<ushort4*>(dst + (long)(d0 + ty + i) * SS + s0 + tx * 4) = w;
  }
}

// ---------- bf16 GEMM, m97-style 128^2 (KV-proj, N=2048: 512 blocks = 2/CU) ----------
template <typename OutT>
__global__ __launch_bounds__(256, 3) void k_gemm(const unsigned short* __restrict__ A,
                                                 const unsigned short* __restrict__ Bt,
                                                 OutT* __restrict__ C,
                                                 int M, int N, int K) {
  __shared__ alignas(16) unsigned short As[128 * 64];
  __shared__ alignas(16) unsigned short Bs[128 * 64];
  const int tid = threadIdx.x;
  const int wave = tid >> 6, lane = tid & 63;
  const int l15 = lane & 15, g = lane >> 4;
  const int wr = wave >> 1, wc = wave & 1;
  const long m0 = (long)blockIdx.y * 128, n0 = (long)blockIdx.x * 128;

  f32x4 acc[4][4] = {{{0.f,0.f,0.f,0.f}}};

  for (long k0 = 0; k0 < K; k0 += 64) {
#pragma unroll
    for (int j = 0; j < 4; ++j) {
      int idx = j * 256 + wave * 64 + lane;
      int row = idx >> 3, sub = idx & 7;
      int sc_ = (sub ^ (row & 7)) * 8;               // pre-swizzled global source
      gload16(A  + (m0 + row) * K + k0 + sc_, (char*)As + (j * 4 + wave) * 1024);
      gload16(Bt + (n0 + row) * K + k0 + sc_, (char*)Bs + (j * 4 + wave) * 1024);
    }
    __syncthreads();
#pragma unroll
    for (int ks = 0; ks < 2; ++ks) {
      short8 a[4], b[4];
#pragma unroll
      for (int m = 0; m < 4; ++m) {
        int row = wr * 64 + m * 16 + l15;
        int cb = (ks * 64 + g * 16) ^ ((row & 7) << 4);   // swizzled read
        a[m] = *reinterpret_cast<const short8*>((const char*)As + row * 128 + cb);
      }
#pragma unroll
      for (int n = 0; n < 4; ++n) {
        int row = wc * 64 + n * 16 + l15;
        int cb = (ks * 64 + g * 16) ^ ((row & 7) << 4);
        b[n] = *reinterpret_cast<const short8*>((const char*)Bs + row * 128 + cb);
      }
#pragma unroll
      for (int m = 0; m < 4; ++m)
#pragma unroll
        for (int n = 0; n < 4; ++n)
          acc[m][n] = mfma16(a[m], b[n], acc[m][n]);
    }
    __syncthreads();
  }

#pragma unroll
  for (int m = 0; m < 4; ++m)
#pragma unroll
    for (int n = 0; n < 4; ++n)
#pragma unroll
      for (int r = 0; r < 4; ++r) {
        long row = m0 + wr * 64 + m * 16 + g * 4 + r;
        long col = n0 + wc * 64 + n * 16 + l15;
        float v = acc[m][n][r];
        if constexpr (sizeof(OutT) == 2) C[row * N + col] = f2bf(v);
        else                             C[row * N + col] = v;
      }
}

// ---------- bf16 GEMM, 256x192 dbuf, ONE barrier per K-tile (Q-proj / out-proj) ----------
template <typename OutT, int NI>
__global__ __launch_bounds__(512, 2) void k_gemm256(const unsigned short* __restrict__ A,
                                                    const unsigned short* __restrict__ Bt,
                                                    OutT* __restrict__ C,
                                                    int M, int N, int K) {
  __shared__ alignas(16) unsigned short As[2][256 * 64];
  __shared__ alignas(16) unsigned short Bs[2][NI * 64 * 64];
  const int tid = threadIdx.x;
  const int lane = tid & 63;
  const int l15 = lane & 15, g = lane >> 4;
  const int wave = tid >> 6;
  const int wm = wave >> 2, wn = wave & 3;

  const int flat = blockIdx.y * gridDim.x + blockIdx.x;
  const int swz = (flat & 7) * ((gridDim.x * gridDim.y) >> 3) + (flat >> 3);
  const long m0 = (long)(swz / gridDim.x) * 256;
  const long n0 = (long)(swz % gridDim.x) * (NI * 64);
  const int nkt = K >> 6;

  f32x4 acc[8][NI];
#pragma unroll
  for (int mi = 0; mi < 8; ++mi)
#pragma unroll
    for (int ni = 0; ni < NI; ++ni)
      acc[mi][ni] = f32x4{0.f, 0.f, 0.f, 0.f};

  auto stage = [&](int buf, int kt) {
#pragma unroll
    for (int j = 0; j < 4; ++j) {                    // A: 256 rows
      int idx = j * 512 + tid;
      int row = idx >> 3, s = idx & 7;
      int ss = s ^ (row & 7);
      gload16(A + (m0 + row) * K + kt * 64 + ss * 8,
              (char*)As[buf] + idx * 16);
    }
#pragma unroll
    for (int j = 0; j < NI; ++j) {                   // B: NI*64 rows
      int idx = j * 512 + tid;
      int row = idx >> 3, s = idx & 7;
      int ss = s ^ (row & 7);
      gload16(Bt + (n0 + row) * K + kt * 64 + ss * 8,
              (char*)Bs[buf] + idx * 16);
    }
  };

  stage(0, 0);
  __syncthreads();

  for (int kt = 0; kt < nkt; ++kt) {
    const int cur = kt & 1;
    if (kt + 1 < nkt) stage(cur ^ 1, kt + 1);        // issue-early (drains late)
    const char* Ab = (const char*)As[cur];
    const char* Bb = (const char*)Bs[cur];

    short8 b[NI][2];
#pragma unroll
    for (int n = 0; n < NI; ++n) {
      int R = wn * (NI * 16) + n * 16 + l15;
#pragma unroll
      for (int kk = 0; kk < 2; ++kk)
        b[n][kk] = *reinterpret_cast<const short8*>(
            Bb + R * 128 + (((kk * 4 + g) ^ (R & 7)) << 4));
    }
    __builtin_amdgcn_s_setprio(1);
#pragma unroll
    for (int mh = 0; mh < 2; ++mh) {
      short8 a[4][2];
#pragma unroll
      for (int m = 0; m < 4; ++m) {
        int R = wm * 128 + mh * 64 + m * 16 + l15;
#pragma unroll
        for (int kk = 0; kk < 2; ++kk)
          a[m][kk] = *reinterpret_cast<const short8*>(
              Ab + R * 128 + (((kk * 4 + g) ^ (R & 7)) << 4));
      }
#pragma unroll
      for (int m = 0; m < 4; ++m)
#pragma unroll
        for (int n = 0; n < NI; ++n)
#pragma unroll
          for (int kk = 0; kk < 2; ++kk)
            acc[mh * 4 + m][n] = mfma16(a[m][kk], b[n][kk], acc[mh * 4 + m][n]);
    }
    __builtin_amdgcn_s_setprio(0);

    __syncthreads();
  }

#pragma unroll
  for (int mi = 0; mi < 8; ++mi)
#pragma unroll
    for (int ni = 0; ni < NI; ++ni)
#pragma unroll
      for (int r = 0; r < 4; ++r) {
        long row = m0 + wm * 128 + mi * 16 + g * 4 + r;
        long col = n0 + wn * (NI * 16) + ni * 16 + l15;
        float v = acc[mi][ni][r];
        if constexpr (sizeof(OutT) == 2) C[row * N + col] = f2bf(v);
        else                             C[row * N + col] = v;
      }
}

// ---------- flash attention: single-buffered K, 5 blocks/CU (occupancy test) ----------
// Same QK/softmax/PV bodies as the r17 verified form; LDS 32KB; per tile:
// {stageV, stageK, vmcnt(0)+barrier, QK, softmax, PV, barrier}.
__global__ __launch_bounds__(256, 5) void k_attn(const unsigned short* __restrict__ Q,
                                                 const unsigned short* __restrict__ KV,
                                                 const unsigned short* __restrict__ VT,
                                                 const float* __restrict__ Mb,
                                                 unsigned short* __restrict__ AO,
                                                 const int* __restrict__ flagp) {
  const int tid = threadIdx.x;
  const int wave = tid >> 6, lane = tid & 63;
  const int l31 = lane & 31, hi = lane >> 5;

  const int bid = blockIdx.x;
  const int id = (bid & 7) * 96 + (bid >> 3);
  const int qt = id & 15;
  const int h  = (id >> 4) % NH;
  const int b  = id / (16 * NH);
  const int kv = h / NREP;
  const int qb = qt * 128 + wave * 32;

  const unsigned short* Qp = Q + ((long)b * SS + qb) * KQ + h * HD;
  const unsigned short* Kp = KV + (long)b * SS * KV2 + kv * HD;
  const unsigned short* Vp = VT + (long)(b * NKV + kv) * HD * SS;
  const float* Mp = Mb + ((long)b * SS + qb + l31) * SS + hi * 4;

  const int msknz = *flagp;
  const float LOG2E = 1.4426950408889634f;

  __shared__ alignas(16) unsigned short Ks[64 * 128];   // 16 KB single-buffer, slot-major
  __shared__ alignas(16) unsigned short Vs[128 * 64];   // 16 KB slot-major

  int koff[8], voff[4];
#pragma unroll
  for (int c = 0; c < 8; ++c)
    koff[c] = (c * 2 + hi) * 1024 + l31 * 16;
#pragma unroll
  for (int ks = 0; ks < 4; ++ks)
    voff[ks] = (ks * 2 + hi) * 2048 + l31 * 16;

  short8 qf[8];
#pragma unroll
  for (int c = 0; c < 8; ++c)
    qf[c] = *reinterpret_cast<const short8*>(Qp + (long)l31 * KQ + c * 16 + hi * 8);

  f32x16 o[4];
#pragma unroll
  for (int dc = 0; dc < 4; ++dc)
#pragma unroll
    for (int r = 0; r < 16; ++r) o[dc][r] = 0.f;
  float mrun = -3e38f, lrun = 0.f;

  auto stageK = [&](int kt) {
#pragma unroll
    for (int j = 0; j < 4; ++j) {
      int s = wave * 4 + j;
      gload16(Kp + (long)(kt + lane) * KV2 + s * 8,
              (char*)Ks + s * 1024);
    }
  };
  auto stageV = [&](int kt) {
#pragma unroll
    for (int j = 0; j < 4; ++j) {
      int u = wave * 4 + j;
      int s = u >> 1, half = u & 1;
      gload16(Vp + (long)(half * 64 + lane) * SS + kt + s * 8,
              (char*)Vs + s * 2048 + half * 1024);
    }
  };

  for (int t = 0; t < SS / 64; ++t) {
    const int kt = t * 64;
    stageV(kt);
    stageK(kt);
    asm volatile("s_waitcnt vmcnt(0)" ::: "memory");   // drain both tiles
    __builtin_amdgcn_s_barrier();                      // publish Ks + Vs

    float4 mk[8];
    if (msknz) {
#pragma unroll
      for (int sb = 0; sb < 2; ++sb)
#pragma unroll
        for (int u = 0; u < 4; ++u)
          mk[sb * 4 + u] = *reinterpret_cast<const float4*>(Mp + kt + sb * 32 + u * 8);
    }

    f32x16 sc0, sc1;
#pragma unroll
    for (int r = 0; r < 16; ++r) { sc0[r] = 0.f; sc1[r] = 0.f; }
    __builtin_amdgcn_s_setprio(1);
#pragma unroll
    for (int sb = 0; sb < 2; ++sb) {
      const char* kbp = (const char*)Ks + sb * 512;
#pragma unroll
      for (int c = 0; c < 8; ++c) {
        short8 kf = *reinterpret_cast<const short8*>(kbp + koff[c]);
        if (sb == 0) sc0 = mfma32(kf, qf[c], sc0);
        else         sc1 = mfma32(kf, qf[c], sc1);
      }
    }
    __builtin_amdgcn_s_setprio(0);

    if (msknz) {
#pragma unroll
      for (int sb = 0; sb < 2; ++sb)
#pragma unroll
        for (int u = 0; u < 4; ++u)
#pragma unroll
          for (int e = 0; e < 4; ++e) {
            int r = u * 4 + e;
            if (sb) sc1[r] = fmaf((&mk[sb * 4 + u].x)[e], LOG2E, sc1[r]);
            else    sc0[r] = fmaf((&mk[sb * 4 + u].x)[e], LOG2E, sc0[r]);
          }
    }
    float ta = -3e38f, tb = -3e38f, tc = -3e38f, td = -3e38f;
#pragma unroll
    for (int r = 0; r < 8; ++r) {
      ta = fmaxf(ta, sc0[r]); tb = fmaxf(tb, sc0[r + 8]);
      tc = fmaxf(tc, sc1[r]); td = fmaxf(td, sc1[r + 8]);
    }
    float tm = fmaxf(fmaxf(ta, tb), fmaxf(tc, td));
    tm = fmaxf(tm, __shfl_xor(tm, 32));

    if (!__all(tm <= mrun + 8.f)) {
      float mn = fmaxf(mrun, tm);
      float corr = __builtin_amdgcn_exp2f(mrun - mn);
      mrun = mn;
      lrun *= corr;
#pragma unroll
      for (int r = 0; r < 16; ++r) {
        int qrow = (r & 3) + 8 * (r >> 2) + 4 * hi;
        float cr = __shfl(corr, qrow);
#pragma unroll
        for (int dc = 0; dc < 4; ++dc) o[dc][r] *= cr;
      }
    }

    float s0a = 0.f, s0b = 0.f, s1a = 0.f, s1b = 0.f;
#pragma unroll
    for (int r = 0; r < 8; ++r) {
      sc0[r]     = __builtin_amdgcn_exp2f(sc0[r] - mrun);     s0a += sc0[r];
      sc0[r + 8] = __builtin_amdgcn_exp2f(sc0[r + 8] - mrun); s0b += sc0[r + 8];
      sc1[r]     = __builtin_amdgcn_exp2f(sc1[r] - mrun);     s1a += sc1[r];
      sc1[r + 8] = __builtin_amdgcn_exp2f(sc1[r + 8] - mrun); s1b += sc1[r + 8];
    }
    float ts = (s0a + s0b) + (s1a + s1b);
    ts += __shfl_xor(ts, 32);
    lrun += ts;

    __builtin_amdgcn_s_setprio(1);
#pragma unroll
    for (int ks = 0; ks < 4; ++ks) {
      const int R = 8 * (ks & 1);
      unsigned int A0, A1, B0, B1;
      if (ks < 2) {
        A0 = cvtpk(sc0[R + 0], sc0[R + 1]); A1 = cvtpk(sc0[R + 2], sc0[R + 3]);
        B0 = cvtpk(sc0[R + 4], sc0[R + 5]); B1 = cvtpk(sc0[R + 6], sc0[R + 7]);
      } else {
        A0 = cvtpk(sc1[R + 0], sc1[R + 1]); A1 = cvtpk(sc1[R + 2], sc1[R + 3]);
        B0 = cvtpk(sc1[R + 4], sc1[R + 5]); B1 = cvtpk(sc1[R + 6], sc1[R + 7]);
      }
      pl32swap(A0, B0);
      pl32swap(A1, B1);
      union { unsigned int w[4]; short8 v; } pa;
      pa.w[0] = A0; pa.w[1] = A1; pa.w[2] = B0; pa.w[3] = B1;
#pragma unroll
      for (int dc = 0; dc < 4; ++dc) {
        short8 vf = *reinterpret_cast<const short8*>((const char*)Vs + voff[ks] + dc * 512);
        o[dc] = mfma32(pa.v, vf, o[dc]);
      }
    }
    __builtin_amdgcn_s_setprio(0);

    __syncthreads();   // all waves done reading Ks/Vs before next-tile staging
  }

  float inv = 1.f / lrun;
#pragma unroll
  for (int r = 0; r < 16; ++r) {
    int qrow = (r & 3) + 8 * (r >> 2) + 4 * hi;
    float ir = __shfl(inv, qrow);
    long row = qb + qrow;
#pragma unroll
    for (int dc = 0; dc < 4; ++dc)
      AO[((long)b * SS + row) * KQ + h * HD + dc * 32 + l31] = f2bf(o[dc][r] * ir);
  }
}

// ---------- launch ----------
extern "C" void kernel_launch(void* const* d_in, const int* in_sizes, int n_in,
                              void* d_out, int out_size, void* d_ws, size_t ws_size,
                              hipStream_t stream) {
  const float* hidden = (const float*)d_in[0];
  const float* mask   = (const float*)d_in[1];
  const float* Wq     = (const float*)d_in[2];
  const float* Wk     = (const float*)d_in[3];
  const float* Wv     = (const float*)d_in[4];
  const float* Wo     = (const float*)d_in[5];

  char* ws = (char*)d_ws;
  constexpr long SZ_X   = (long)MM * HH * 2;          // 25.2 MB bf16
  constexpr long SZ_WQT = (long)HH * KQ * 2;          // 18.9 MB
  constexpr long SZ_WKT = (long)HH * KKV * 2;         // 6.3 MB
  constexpr long SZ_QKV = (long)MM * KKV * 2;         // 8.4 MB
  unsigned short* Xb  = (unsigned short*)(ws);
  unsigned short* WqT = (unsigned short*)(ws + SZ_X);
  unsigned short* WkT = (unsigned short*)(ws + SZ_X + SZ_WQT);   // [1024][3072]
  unsigned short* WvT = (unsigned short*)(ws + SZ_X + SZ_WQT + SZ_WKT); // contiguous
  unsigned short* WoT = (unsigned short*)(ws + SZ_X + SZ_WQT + 2 * SZ_WKT);
  unsigned short* Qb  = (unsigned short*)(ws + SZ_X + 2 * SZ_WQT + 2 * SZ_WKT);
  unsigned short* KVb = (unsigned short*)(ws + 2 * SZ_X + 2 * SZ_WQT + 2 * SZ_WKT); // [4096][2048]
  unsigned short* VTb = (unsigned short*)(ws + 2 * SZ_X + 2 * SZ_WQT + 2 * SZ_WKT + 2 * SZ_QKV);
  unsigned short* AOb = (unsigned short*)(ws + 2 * SZ_X + 2 * SZ_WQT + 2 * SZ_WKT + 3 * SZ_QKV);
  int* flagp = (int*)(ws + 2 * SZ_X + 2 * SZ_WQT + 2 * SZ_WKT + 4 * SZ_QKV); // after VTb

  const float QSCALE = 0.08838834764831845f * 1.4426950408889634f;

  // 1) flag zero; fused hidden-convert + mask-flag; all-weight transpose (one launch)
  hipMemsetAsync(flagp, 0, sizeof(int), stream);
  k_prep<<<2048, 256, 0, stream>>>(hidden, Xb, MM * HH / 4, mask, BB * SS * SS / 4, flagp);
  k_tcvt4<<<dim3(KQ / 32, HH / 32, 4), 256, 0, stream>>>(Wq, Wo, Wk, Wv,
                                                         WqT, WoT, WkT, WvT, QSCALE);

  // 2) projections: Q via 256x192 dbuf; K|V fused via m97 128^2 (512 blocks = 2/CU)
  k_gemm256<unsigned short, 3><<<dim3(KQ / 192, MM / 256), 512, 0, stream>>>(Xb, WqT, Qb, MM, KQ, HH);
  k_gemm<unsigned short><<<dim3(KV2 / 128, MM / 128), 256, 0, stream>>>(Xb, WkT, KVb, MM, KV2, HH);

  // 3) V -> V^T (64x64 tiles, ushort4 I/O)
  k_vt<<<dim3(HD / 64, SS / 64, BB * NKV), 256, 0, stream>>>(KVb, VTb);

  // 4) attention (single-buffered K, 5 blocks/CU occupancy test)
  k_attn<<<16 * NH * BB, 256, 0, stream>>>(Qb, KVb, VTb, mask, AOb, flagp);

  // 5) output projection via 256x192 dbuf -> fp32 d_out
  k_gemm256<float, 3><<<dim3(HH / 192, MM / 256), 512, 0, stream>>>(AOb, WoT, (float*)d_out, MM, HH, HH);
}

// Round 23
// 434.752 us; speedup vs baseline: 2.4570x; 2.4570x over previous
//
#include <hip/hip_runtime.h>
#include <hip/hip_bf16.h>
#include <stdint.h>

typedef __attribute__((ext_vector_type(8))) short short8;
typedef __attribute__((ext_vector_type(4))) float f32x4;
typedef __attribute__((ext_vector_type(16))) float f32x16;

#define DEVINL static __device__ __forceinline__

// ---------- helpers ----------
DEVINL unsigned short f2bf(float x) {
  union { float f; unsigned int u; } c; c.f = x;
  unsigned int u = c.u;
  u += 0x7fffu + ((u >> 16) & 1u);   // RNE
  return (unsigned short)(u >> 16);
}

DEVINL f32x4 mfma16(short8 a, short8 b, f32x4 c) {
  return __builtin_amdgcn_mfma_f32_16x16x32_bf16(a, b, c, 0, 0, 0);
}

DEVINL f32x16 mfma32(short8 a, short8 b, f32x16 c) {
  return __builtin_amdgcn_mfma_f32_32x32x16_bf16(a, b, c, 0, 0, 0);
}

DEVINL unsigned int cvtpk(float lo, float hi_) {
  unsigned int r;
  asm("v_cvt_pk_bf16_f32 %0, %1, %2" : "=v"(r) : "v"(lo), "v"(hi_));
  return r;
}

DEVINL void pl32swap(unsigned int& a, unsigned int& b) {
  asm("v_permlane32_swap_b32 %0, %1" : "+v"(a), "+v"(b));
}

DEVINL void gload16(const void* g, void* l) {
  __builtin_amdgcn_global_load_lds((const __attribute__((address_space(1))) void*)g,
                                   (__attribute__((address_space(3))) void*)l, 16, 0, 0);
}

// ---------- problem constants ----------
static constexpr int BB = 2, SS = 2048, HH = 3072;
static constexpr int NH = 24, NKV = 8, HD = 128, NREP = 3;
static constexpr int MM = BB * SS;            // 4096 token rows
static constexpr int KQ = NH * HD;            // 3072
static constexpr int KKV = NKV * HD;          // 1024
static constexpr int KV2 = 2 * KKV;           // 2048 (fused K|V row stride)

// ---------- fused prep: hidden fp32->bf16 + mask nonzero flag (grid-strided) ----------
__global__ void k_prep(const float* __restrict__ hidden, unsigned short* __restrict__ outX,
                       int n4x, const float* __restrict__ mask, int n4m,
                       int* __restrict__ flag) {
  const int stride = gridDim.x * 256;
  const int t0 = blockIdx.x * 256 + threadIdx.x;
  for (int i = t0; i < n4x; i += stride) {
    float4 v = reinterpret_cast<const float4*>(hidden)[i];
    ushort4 o;
    o.x = f2bf(v.x); o.y = f2bf(v.y); o.z = f2bf(v.z); o.w = f2bf(v.w);
    reinterpret_cast<ushort4*>(outX)[i] = o;
  }
  bool any = false;
  for (int i = t0; i < n4m; i += stride) {
    float4 v = reinterpret_cast<const float4*>(mask)[i];
    any |= (v.x != 0.f) || (v.y != 0.f) || (v.z != 0.f) || (v.w != 0.f);
  }
  if (__any(any) && (threadIdx.x & 63) == 0) atomicOr(flag, 1);
}

// ---------- all-weights transpose+convert: z selects {Wq,Wo,Wk,Wv} ----------
__global__ void k_tcvt4(const float* __restrict__ Wq, const float* __restrict__ Wo,
                        const float* __restrict__ Wk, const float* __restrict__ Wv,
                        unsigned short* __restrict__ WqT, unsigned short* __restrict__ WoT,
                        unsigned short* __restrict__ WkT, unsigned short* __restrict__ WvT,
                        float qscale) {
  __shared__ float t[32][33];
  const int z = blockIdx.z;
  const int C = (z < 2) ? KQ : KKV;
  const int c0 = blockIdx.x * 32;
  if (c0 >= C) return;
  const float* in = (z == 0) ? Wq : (z == 1) ? Wo : (z == 2) ? Wk : Wv;
  unsigned short* out = (z == 0) ? WqT : (z == 1) ? WoT : (z == 2) ? WkT : WvT;
  const float sc = (z == 0) ? qscale : 1.0f;
  int tx = threadIdx.x & 31, ty = threadIdx.x >> 5;
  int r0 = blockIdx.y * 32;
#pragma unroll
  for (int i = 0; i < 32; i += 8)
    t[ty + i][tx] = in[(long)(r0 + ty + i) * C + c0 + tx];
  __syncthreads();
#pragma unroll
  for (int i = 0; i < 32; i += 8)
    out[(long)(c0 + ty + i) * HH + r0 + tx] = f2bf(t[tx][ty + i] * sc);
}

// ---------- V transpose (bf16), 64x64 tiles, ushort4 I/O ----------
__global__ void k_vt(const unsigned short* __restrict__ KV, unsigned short* __restrict__ VT) {
  __shared__ unsigned short t[64][66];
  int b = blockIdx.z >> 3, kv = blockIdx.z & 7;
  int tx = threadIdx.x & 15, ty = threadIdx.x >> 4;   // 16 x 16
  int d0 = blockIdx.x * 64, s0 = blockIdx.y * 64;
  const unsigned short* src = KV + ((long)b * SS) * KV2 + KKV + kv * HD;
  unsigned short* dst = VT + (long)(b * NKV + kv) * HD * SS;
#pragma unroll
  for (int i = 0; i < 64; i += 16) {
    ushort4 v = *reinterpret_cast<const ushort4*>(src + (long)(s0 + ty + i) * KV2 + d0 + tx * 4);
    t[ty + i][tx * 4 + 0] = v.x; t[ty + i][tx * 4 + 1] = v.y;
    t[ty + i][tx * 4 + 2] = v.z; t[ty + i][tx * 4 + 3] = v.w;
  }
  __syncthreads();
#pragma unroll
  for (int i = 0; i < 64; i += 16) {
    ushort4 w;
    w.x = t[tx * 4 + 0][ty + i]; w.y = t[tx * 4 + 1][ty + i];
    w.z = t[tx * 4 + 2][ty + i]; w.w = t[tx * 4 + 3][ty + i];
    *reinterpret_cast<ushort4*>(dst + (long)(d0 + ty + i) * SS + s0 + tx * 4) = w;
  }
}

// ---------- bf16 GEMM, m97-style 128^2 (KV-proj, N=2048: 512 blocks = 2/CU) ----------
template <typename OutT>
__global__ __launch_bounds__(256, 3) void k_gemm(const unsigned short* __restrict__ A,
                                                 const unsigned short* __restrict__ Bt,
                                                 OutT* __restrict__ C,
                                                 int M, int N, int K) {
  __shared__ alignas(16) unsigned short As[128 * 64];
  __shared__ alignas(16) unsigned short Bs[128 * 64];
  const int tid = threadIdx.x;
  const int wave = tid >> 6, lane = tid & 63;
  const int l15 = lane & 15, g = lane >> 4;
  const int wr = wave >> 1, wc = wave & 1;
  const long m0 = (long)blockIdx.y * 128, n0 = (long)blockIdx.x * 128;

  f32x4 acc[4][4] = {{{0.f,0.f,0.f,0.f}}};

  for (long k0 = 0; k0 < K; k0 += 64) {
#pragma unroll
    for (int j = 0; j < 4; ++j) {
      int idx = j * 256 + wave * 64 + lane;
      int row = idx >> 3, sub = idx & 7;
      int sc_ = (sub ^ (row & 7)) * 8;               // pre-swizzled global source
      gload16(A  + (m0 + row) * K + k0 + sc_, (char*)As + (j * 4 + wave) * 1024);
      gload16(Bt + (n0 + row) * K + k0 + sc_, (char*)Bs + (j * 4 + wave) * 1024);
    }
    __syncthreads();
#pragma unroll
    for (int ks = 0; ks < 2; ++ks) {
      short8 a[4], b[4];
#pragma unroll
      for (int m = 0; m < 4; ++m) {
        int row = wr * 64 + m * 16 + l15;
        int cb = (ks * 64 + g * 16) ^ ((row & 7) << 4);   // swizzled read
        a[m] = *reinterpret_cast<const short8*>((const char*)As + row * 128 + cb);
      }
#pragma unroll
      for (int n = 0; n < 4; ++n) {
        int row = wc * 64 + n * 16 + l15;
        int cb = (ks * 64 + g * 16) ^ ((row & 7) << 4);
        b[n] = *reinterpret_cast<const short8*>((const char*)Bs + row * 128 + cb);
      }
#pragma unroll
      for (int m = 0; m < 4; ++m)
#pragma unroll
        for (int n = 0; n < 4; ++n)
          acc[m][n] = mfma16(a[m], b[n], acc[m][n]);
    }
    __syncthreads();
  }

#pragma unroll
  for (int m = 0; m < 4; ++m)
#pragma unroll
    for (int n = 0; n < 4; ++n)
#pragma unroll
      for (int r = 0; r < 4; ++r) {
        long row = m0 + wr * 64 + m * 16 + g * 4 + r;
        long col = n0 + wc * 64 + n * 16 + l15;
        float v = acc[m][n][r];
        if constexpr (sizeof(OutT) == 2) C[row * N + col] = f2bf(v);
        else                             C[row * N + col] = v;
      }
}

// ---------- bf16 GEMM, 256x192 dbuf, ONE barrier per K-tile (Q-proj / out-proj) ----------
template <typename OutT, int NI>
__global__ __launch_bounds__(512, 2) void k_gemm256(const unsigned short* __restrict__ A,
                                                    const unsigned short* __restrict__ Bt,
                                                    OutT* __restrict__ C,
                                                    int M, int N, int K) {
  __shared__ alignas(16) unsigned short As[2][256 * 64];
  __shared__ alignas(16) unsigned short Bs[2][NI * 64 * 64];
  const int tid = threadIdx.x;
  const int lane = tid & 63;
  const int l15 = lane & 15, g = lane >> 4;
  const int wave = tid >> 6;
  const int wm = wave >> 2, wn = wave & 3;

  const int flat = blockIdx.y * gridDim.x + blockIdx.x;
  const int swz = (flat & 7) * ((gridDim.x * gridDim.y) >> 3) + (flat >> 3);
  const long m0 = (long)(swz / gridDim.x) * 256;
  const long n0 = (long)(swz % gridDim.x) * (NI * 64);
  const int nkt = K >> 6;

  f32x4 acc[8][NI];
#pragma unroll
  for (int mi = 0; mi < 8; ++mi)
#pragma unroll
    for (int ni = 0; ni < NI; ++ni)
      acc[mi][ni] = f32x4{0.f, 0.f, 0.f, 0.f};

  auto stage = [&](int buf, int kt) {
#pragma unroll
    for (int j = 0; j < 4; ++j) {                    // A: 256 rows
      int idx = j * 512 + tid;
      int row = idx >> 3, s = idx & 7;
      int ss = s ^ (row & 7);
      gload16(A + (m0 + row) * K + kt * 64 + ss * 8,
              (char*)As[buf] + idx * 16);
    }
#pragma unroll
    for (int j = 0; j < NI; ++j) {                   // B: NI*64 rows
      int idx = j * 512 + tid;
      int row = idx >> 3, s = idx & 7;
      int ss = s ^ (row & 7);
      gload16(Bt + (n0 + row) * K + kt * 64 + ss * 8,
              (char*)Bs[buf] + idx * 16);
    }
  };

  stage(0, 0);
  __syncthreads();

  for (int kt = 0; kt < nkt; ++kt) {
    const int cur = kt & 1;
    if (kt + 1 < nkt) stage(cur ^ 1, kt + 1);        // issue-early (drains late)
    const char* Ab = (const char*)As[cur];
    const char* Bb = (const char*)Bs[cur];

    short8 b[NI][2];
#pragma unroll
    for (int n = 0; n < NI; ++n) {
      int R = wn * (NI * 16) + n * 16 + l15;
#pragma unroll
      for (int kk = 0; kk < 2; ++kk)
        b[n][kk] = *reinterpret_cast<const short8*>(
            Bb + R * 128 + (((kk * 4 + g) ^ (R & 7)) << 4));
    }
    __builtin_amdgcn_s_setprio(1);
#pragma unroll
    for (int mh = 0; mh < 2; ++mh) {
      short8 a[4][2];
#pragma unroll
      for (int m = 0; m < 4; ++m) {
        int R = wm * 128 + mh * 64 + m * 16 + l15;
#pragma unroll
        for (int kk = 0; kk < 2; ++kk)
          a[m][kk] = *reinterpret_cast<const short8*>(
              Ab + R * 128 + (((kk * 4 + g) ^ (R & 7)) << 4));
      }
#pragma unroll
      for (int m = 0; m < 4; ++m)
#pragma unroll
        for (int n = 0; n < NI; ++n)
#pragma unroll
          for (int kk = 0; kk < 2; ++kk)
            acc[mh * 4 + m][n] = mfma16(a[m][kk], b[n][kk], acc[mh * 4 + m][n]);
    }
    __builtin_amdgcn_s_setprio(0);

    __syncthreads();
  }

#pragma unroll
  for (int mi = 0; mi < 8; ++mi)
#pragma unroll
    for (int ni = 0; ni < NI; ++ni)
#pragma unroll
      for (int r = 0; r < 4; ++r) {
        long row = m0 + wm * 128 + mi * 16 + g * 4 + r;
        long col = n0 + wn * (NI * 16) + ni * 16 + l15;
        float v = acc[mi][ni][r];
        if constexpr (sizeof(OutT) == 2) C[row * N + col] = f2bf(v);
        else                             C[row * N + col] = v;
      }
}

// ---------- flash attention: slot-major LDS (0 conflicts), in-reg softmax ----------
// Round-17/21 verified form (K dbuf, counted vmcnt(4), sb-outer QK) — exact.
__global__ __launch_bounds__(256, 3) void k_attn(const unsigned short* __restrict__ Q,
                                                 const unsigned short* __restrict__ KV,
                                                 const unsigned short* __restrict__ VT,
                                                 const float* __restrict__ Mb,
                                                 unsigned short* __restrict__ AO,
                                                 const int* __restrict__ flagp) {
  const int tid = threadIdx.x;
  const int wave = tid >> 6, lane = tid & 63;
  const int l31 = lane & 31, hi = lane >> 5;

  const int bid = blockIdx.x;
  const int id = (bid & 7) * 96 + (bid >> 3);
  const int qt = id & 15;
  const int h  = (id >> 4) % NH;
  const int b  = id / (16 * NH);
  const int kv = h / NREP;
  const int qb = qt * 128 + wave * 32;

  const unsigned short* Qp = Q + ((long)b * SS + qb) * KQ + h * HD;
  const unsigned short* Kp = KV + (long)b * SS * KV2 + kv * HD;
  const unsigned short* Vp = VT + (long)(b * NKV + kv) * HD * SS;
  const float* Mp = Mb + ((long)b * SS + qb + l31) * SS + hi * 4;

  const int msknz = *flagp;
  const float LOG2E = 1.4426950408889634f;

  __shared__ alignas(16) unsigned short Ks[2][64 * 128];   // slot-major dbuf
  __shared__ alignas(16) unsigned short Vs[128 * 64];      // slot-major

  int koff[8], voff[4];
#pragma unroll
  for (int c = 0; c < 8; ++c)
    koff[c] = (c * 2 + hi) * 1024 + l31 * 16;
#pragma unroll
  for (int ks = 0; ks < 4; ++ks)
    voff[ks] = (ks * 2 + hi) * 2048 + l31 * 16;

  short8 qf[8];
#pragma unroll
  for (int c = 0; c < 8; ++c)
    qf[c] = *reinterpret_cast<const short8*>(Qp + (long)l31 * KQ + c * 16 + hi * 8);

  f32x16 o[4];
#pragma unroll
  for (int dc = 0; dc < 4; ++dc)
#pragma unroll
    for (int r = 0; r < 16; ++r) o[dc][r] = 0.f;
  float mrun = -3e38f, lrun = 0.f;

  auto stageK = [&](int buf, int kt) {
#pragma unroll
    for (int j = 0; j < 4; ++j) {
      int s = wave * 4 + j;
      gload16(Kp + (long)(kt + lane) * KV2 + s * 8,
              (char*)Ks[buf] + s * 1024);
    }
  };
  auto stageV = [&](int kt) {
#pragma unroll
    for (int j = 0; j < 4; ++j) {
      int u = wave * 4 + j;
      int s = u >> 1, half = u & 1;
      gload16(Vp + (long)(half * 64 + lane) * SS + kt + s * 8,
              (char*)Vs + s * 2048 + half * 1024);
    }
  };

  stageK(0, 0);
  __syncthreads();

  for (int t = 0; t < SS / 64; ++t) {
    const int kt = t * 64;
    const bool last = (t == SS / 64 - 1);
    stageV(kt);
    if (!last) stageK((t + 1) & 1, kt + 64);

    float4 mk[8];
    if (msknz) {
#pragma unroll
      for (int sb = 0; sb < 2; ++sb)
#pragma unroll
        for (int u = 0; u < 4; ++u)
          mk[sb * 4 + u] = *reinterpret_cast<const float4*>(Mp + kt + sb * 32 + u * 8);
    }

    f32x16 sc0, sc1;
#pragma unroll
    for (int r = 0; r < 16; ++r) { sc0[r] = 0.f; sc1[r] = 0.f; }
    __builtin_amdgcn_s_setprio(1);
#pragma unroll
    for (int sb = 0; sb < 2; ++sb) {
      const char* kbp = (const char*)Ks[t & 1] + sb * 512;
#pragma unroll
      for (int c = 0; c < 8; ++c) {
        short8 kf = *reinterpret_cast<const short8*>(kbp + koff[c]);
        if (sb == 0) sc0 = mfma32(kf, qf[c], sc0);
        else         sc1 = mfma32(kf, qf[c], sc1);
      }
    }
    __builtin_amdgcn_s_setprio(0);

    if (msknz) {
#pragma unroll
      for (int sb = 0; sb < 2; ++sb)
#pragma unroll
        for (int u = 0; u < 4; ++u)
#pragma unroll
          for (int e = 0; e < 4; ++e) {
            int r = u * 4 + e;
            if (sb) sc1[r] = fmaf((&mk[sb * 4 + u].x)[e], LOG2E, sc1[r]);
            else    sc0[r] = fmaf((&mk[sb * 4 + u].x)[e], LOG2E, sc0[r]);
          }
    }
    float ta = -3e38f, tb = -3e38f, tc = -3e38f, td = -3e38f;
#pragma unroll
    for (int r = 0; r < 8; ++r) {
      ta = fmaxf(ta, sc0[r]); tb = fmaxf(tb, sc0[r + 8]);
      tc = fmaxf(tc, sc1[r]); td = fmaxf(td, sc1[r + 8]);
    }
    float tm = fmaxf(fmaxf(ta, tb), fmaxf(tc, td));
    tm = fmaxf(tm, __shfl_xor(tm, 32));

    if (!__all(tm <= mrun + 8.f)) {
      float mn = fmaxf(mrun, tm);
      float corr = __builtin_amdgcn_exp2f(mrun - mn);
      mrun = mn;
      lrun *= corr;
#pragma unroll
      for (int r = 0; r < 16; ++r) {
        int qrow = (r & 3) + 8 * (r >> 2) + 4 * hi;
        float cr = __shfl(corr, qrow);
#pragma unroll
        for (int dc = 0; dc < 4; ++dc) o[dc][r] *= cr;
      }
    }

    float s0a = 0.f, s0b = 0.f, s1a = 0.f, s1b = 0.f;
#pragma unroll
    for (int r = 0; r < 8; ++r) {
      sc0[r]     = __builtin_amdgcn_exp2f(sc0[r] - mrun);     s0a += sc0[r];
      sc0[r + 8] = __builtin_amdgcn_exp2f(sc0[r + 8] - mrun); s0b += sc0[r + 8];
      sc1[r]     = __builtin_amdgcn_exp2f(sc1[r] - mrun);     s1a += sc1[r];
      sc1[r + 8] = __builtin_amdgcn_exp2f(sc1[r + 8] - mrun); s1b += sc1[r + 8];
    }
    float ts = (s0a + s0b) + (s1a + s1b);
    ts += __shfl_xor(ts, 32);
    lrun += ts;

    if (!last) asm volatile("s_waitcnt vmcnt(4)" ::: "memory");
    else       asm volatile("s_waitcnt vmcnt(0)" ::: "memory");
    __builtin_amdgcn_s_barrier();

    __builtin_amdgcn_s_setprio(1);
#pragma unroll
    for (int ks = 0; ks < 4; ++ks) {
      const int R = 8 * (ks & 1);
      unsigned int A0, A1, B0, B1;
      if (ks < 2) {
        A0 = cvtpk(sc0[R + 0], sc0[R + 1]); A1 = cvtpk(sc0[R + 2], sc0[R + 3]);
        B0 = cvtpk(sc0[R + 4], sc0[R + 5]); B1 = cvtpk(sc0[R + 6], sc0[R + 7]);
      } else {
        A0 = cvtpk(sc1[R + 0], sc1[R + 1]); A1 = cvtpk(sc1[R + 2], sc1[R + 3]);
        B0 = cvtpk(sc1[R + 4], sc1[R + 5]); B1 = cvtpk(sc1[R + 6], sc1[R + 7]);
      }
      pl32swap(A0, B0);
      pl32swap(A1, B1);
      union { unsigned int w[4]; short8 v; } pa;
      pa.w[0] = A0; pa.w[1] = A1; pa.w[2] = B0; pa.w[3] = B1;
#pragma unroll
      for (int dc = 0; dc < 4; ++dc) {
        short8 vf = *reinterpret_cast<const short8*>((const char*)Vs + voff[ks] + dc * 512);
        o[dc] = mfma32(pa.v, vf, o[dc]);
      }
    }
    __builtin_amdgcn_s_setprio(0);

    __syncthreads();
  }

  float inv = 1.f / lrun;
#pragma unroll
  for (int r = 0; r < 16; ++r) {
    int qrow = (r & 3) + 8 * (r >> 2) + 4 * hi;
    float ir = __shfl(inv, qrow);
    long row = qb + qrow;
#pragma unroll
    for (int dc = 0; dc < 4; ++dc)
      AO[((long)b * SS + row) * KQ + h * HD + dc * 32 + l31] = f2bf(o[dc][r] * ir);
  }
}

// ---------- launch ----------
extern "C" void kernel_launch(void* const* d_in, const int* in_sizes, int n_in,
                              void* d_out, int out_size, void* d_ws, size_t ws_size,
                              hipStream_t stream) {
  const float* hidden = (const float*)d_in[0];
  const float* mask   = (const float*)d_in[1];
  const float* Wq     = (const float*)d_in[2];
  const float* Wk     = (const float*)d_in[3];
  const float* Wv     = (const float*)d_in[4];
  const float* Wo     = (const float*)d_in[5];

  char* ws = (char*)d_ws;
  constexpr long SZ_X   = (long)MM * HH * 2;          // 25.2 MB bf16
  constexpr long SZ_WQT = (long)HH * KQ * 2;          // 18.9 MB
  constexpr long SZ_WKT = (long)HH * KKV * 2;         // 6.3 MB
  constexpr long SZ_QKV = (long)MM * KKV * 2;         // 8.4 MB
  unsigned short* Xb  = (unsigned short*)(ws);
  unsigned short* WqT = (unsigned short*)(ws + SZ_X);
  unsigned short* WkT = (unsigned short*)(ws + SZ_X + SZ_WQT);   // [1024][3072]
  unsigned short* WvT = (unsigned short*)(ws + SZ_X + SZ_WQT + SZ_WKT); // contiguous
  unsigned short* WoT = (unsigned short*)(ws + SZ_X + SZ_WQT + 2 * SZ_WKT);
  unsigned short* Qb  = (unsigned short*)(ws + SZ_X + 2 * SZ_WQT + 2 * SZ_WKT);
  unsigned short* KVb = (unsigned short*)(ws + 2 * SZ_X + 2 * SZ_WQT + 2 * SZ_WKT); // [4096][2048]
  unsigned short* VTb = (unsigned short*)(ws + 2 * SZ_X + 2 * SZ_WQT + 2 * SZ_WKT + 2 * SZ_QKV);
  unsigned short* AOb = (unsigned short*)(ws + 2 * SZ_X + 2 * SZ_WQT + 2 * SZ_WKT + 3 * SZ_QKV);
  int* flagp = (int*)(ws + 2 * SZ_X + 2 * SZ_WQT + 2 * SZ_WKT + 4 * SZ_QKV); // after VTb

  const float QSCALE = 0.08838834764831845f * 1.4426950408889634f;

  // 1) flag zero; fused hidden-convert + mask-flag; all-weight transpose (one launch)
  hipMemsetAsync(flagp, 0, sizeof(int), stream);
  k_prep<<<2048, 256, 0, stream>>>(hidden, Xb, MM * HH / 4, mask, BB * SS * SS / 4, flagp);
  k_tcvt4<<<dim3(KQ / 32, HH / 32, 4), 256, 0, stream>>>(Wq, Wo, Wk, Wv,
                                                         WqT, WoT, WkT, WvT, QSCALE);

  // 2) projections: Q via 256x192 dbuf; K|V fused via m97 128^2 (512 blocks = 2/CU)
  k_gemm256<unsigned short, 3><<<dim3(KQ / 192, MM / 256), 512, 0, stream>>>(Xb, WqT, Qb, MM, KQ, HH);
  k_gemm<unsigned short><<<dim3(KV2 / 128, MM / 128), 256, 0, stream>>>(Xb, WkT, KVb, MM, KV2, HH);

  // 3) V -> V^T (64x64 tiles, ushort4 I/O)
  k_vt<<<dim3(HD / 64, SS / 64, BB * NKV), 256, 0, stream>>>(KVb, VTb);

  // 4) attention (round-17/21 verified form)
  k_attn<<<16 * NH * BB, 256, 0, stream>>>(Qb, KVb, VTb, mask, AOb, flagp);

  // 5) output projection via 256x192 dbuf -> fp32 d_out
  k_gemm256<float, 3><<<dim3(HH / 192, MM / 256), 512, 0, stream>>>(AOb, WoT, (float*)d_out, MM, HH, HH);
}